// Round 3
// baseline (440.358 us; speedup 1.0000x reference)
//
#include <hip/hip_runtime.h>

#define N_COLS 4096
#define BLOCK 256
#define EPS 1e-7f

// clang-native vector type for nontemporal builtins (HIP's float4 is a class)
typedef float floatx4 __attribute__((ext_vector_type(4)));

// compare-exchange keeping the LARGER value in `a` (descending order)
__device__ __forceinline__ void cswap_desc(float& a, float& b) {
    float hi = fmaxf(a, b);
    b = fminf(a, b);
    a = hi;
}

// Batcher odd-even mergesort for 8 elements, 19 comparators, descending.
__device__ __forceinline__ void sort8_desc(float v[8]) {
    cswap_desc(v[0], v[1]); cswap_desc(v[2], v[3]); cswap_desc(v[4], v[5]); cswap_desc(v[6], v[7]);
    cswap_desc(v[0], v[2]); cswap_desc(v[1], v[3]); cswap_desc(v[4], v[6]); cswap_desc(v[5], v[7]);
    cswap_desc(v[1], v[2]); cswap_desc(v[5], v[6]);
    cswap_desc(v[0], v[4]); cswap_desc(v[1], v[5]); cswap_desc(v[2], v[6]); cswap_desc(v[3], v[7]);
    cswap_desc(v[2], v[4]); cswap_desc(v[3], v[5]);
    cswap_desc(v[1], v[2]); cswap_desc(v[3], v[4]); cswap_desc(v[5], v[6]);
}

// Merge sorted-desc b[8] into sorted-desc a[8], keeping the top-8 (sorted desc).
// Bitonic split (max(a[i], b[7-i])) + 3-stage bitonic clean (12 comparators).
__device__ __forceinline__ void merge8(float a[8], const float b[8]) {
    float t[8];
#pragma unroll
    for (int i = 0; i < 8; ++i) t[i] = fmaxf(a[i], b[7 - i]);
    cswap_desc(t[0], t[4]); cswap_desc(t[1], t[5]); cswap_desc(t[2], t[6]); cswap_desc(t[3], t[7]);
    cswap_desc(t[0], t[2]); cswap_desc(t[1], t[3]); cswap_desc(t[4], t[6]); cswap_desc(t[5], t[7]);
    cswap_desc(t[0], t[1]); cswap_desc(t[2], t[3]); cswap_desc(t[4], t[5]); cswap_desc(t[6], t[7]);
#pragma unroll
    for (int i = 0; i < 8; ++i) a[i] = t[i];
}

__global__ __launch_bounds__(BLOCK, 8) void sparse_attn_topk_kernel(
    const float* __restrict__ in, float* __restrict__ out) {
    const int row  = blockIdx.x;
    const int tid  = threadIdx.x;   // 0..255
    const int lane = tid & 63;
    const int wave = tid >> 6;      // 0..3

    const size_t base = (size_t)row * N_COLS;
    const float4* in4 = reinterpret_cast<const float4*>(in + base);
    floatx4* out4     = reinterpret_cast<floatx4*>(out + base);

    // ---- pass 1: per-thread top-8 of 16 values (not retained in regs) ----
    float a[8], b[8];
    {
        float4 v0 = in4[tid + 0 * BLOCK];
        float4 v1 = in4[tid + 1 * BLOCK];
        a[0] = v0.x; a[1] = v0.y; a[2] = v0.z; a[3] = v0.w;
        a[4] = v1.x; a[5] = v1.y; a[6] = v1.z; a[7] = v1.w;
        sort8_desc(a);
        float4 v2 = in4[tid + 2 * BLOCK];
        float4 v3 = in4[tid + 3 * BLOCK];
        b[0] = v2.x; b[1] = v2.y; b[2] = v2.z; b[3] = v2.w;
        b[4] = v3.x; b[5] = v3.y; b[6] = v3.z; b[7] = v3.w;
        sort8_desc(b);
        merge8(a, b);
    }

    // ---- wave-level butterfly: all 64 lanes converge to wave top-8 ----
#pragma unroll
    for (int d = 1; d < 64; d <<= 1) {
#pragma unroll
        for (int i = 0; i < 8; ++i) b[i] = __shfl_xor(a[i], d, 64);
        merge8(a, b);
    }

    // ---- cross-wave merge via LDS (4 waves, one barrier) ----
    __shared__ alignas(16) float s_top[4][8];
    if (lane == 0) {
#pragma unroll
        for (int i = 0; i < 8; ++i) s_top[wave][i] = a[i];
    }
    __syncthreads();
#pragma unroll
    for (int w = 0; w < 4; ++w) {
        if (w != wave) {  // wave-uniform branch
#pragma unroll
            for (int i = 0; i < 8; ++i) b[i] = s_top[w][i];
            merge8(a, b);
        }
    }

    const float delta = a[7] + EPS;  // 8th largest + eps

    // Every row element > topv[7] is contained in the top-8 multiset, and
    // elements == topv[7] clip to exactly 0. So the full-row clipped sum
    // equals the clipped sum over the merged top-8 — no second reduction.
    float total = 0.0f;
#pragma unroll
    for (int i = 0; i < 8; ++i) total += fmaxf(a[i] - delta, 0.0f);
    const float inv = 1.0f / (total + EPS);

    // ---- pass 2: re-read row (L1/L2-hot, 16 KB/block) and stream out ----
#pragma unroll
    for (int k = 0; k < 4; ++k) {
        float4 v = in4[tid + k * BLOCK];
        floatx4 o;
        o.x = fmaxf(v.x - delta, 0.0f) * inv;
        o.y = fmaxf(v.y - delta, 0.0f) * inv;
        o.z = fmaxf(v.z - delta, 0.0f) * inv;
        o.w = fmaxf(v.w - delta, 0.0f) * inv;
        __builtin_nontemporal_store(o, &out4[tid + k * BLOCK]);
    }
}

extern "C" void kernel_launch(void* const* d_in, const int* in_sizes, int n_in,
                              void* d_out, int out_size, void* d_ws, size_t ws_size,
                              hipStream_t stream) {
    const float* attn_s = (const float*)d_in[0];
    float* out = (float*)d_out;
    const int n_rows = in_sizes[0] / N_COLS;  // 16384
    sparse_attn_topk_kernel<<<n_rows, BLOCK, 0, stream>>>(attn_s, out);
}